// Round 15
// baseline (978.788 us; speedup 1.0000x reference)
//
#include <hip/hip_runtime.h>

// SRU forward, MI355X. B=16, T=2048, D=1024, L=4.
// H stored as int16-split i8 pair (scale 4096). W single i8 (scale 2^11).
// GEMM: 2-product i8 MFMA (ah.w, al.w), exact int32 acc, 128x128 tile,
//   4 waves, BK=64. A staged via global_load_lds (2-buffer, XOR-swizzled,
//   counted vmcnt + raw s_barrier pairs). B read DIRECTLY from global into
//   registers each K-step (W is L2/L3-resident; removes 35% of LDS traffic).
//   Issue order per step-tail: loadB(k+1) then stage(k+2); steady wait
//   vmcnt(4) retires S(k),B(k) leaving S(k+1) in flight.
//   __launch_bounds__(256,2) — (256,3) spills AccVGPR acc (R11).
//   Fused epilogue (Ux raw f16, Uf/Ur sigmoid'd f16); per-b length tile-skip;
//   last layer computes zr only for the len-1 tile. XCD-aware 1D grid.
// Scan: ONE kernel per layer: 8 waves x 256-t spans; phase A per-span (P,L),
//   LDS combine -> exact c_init, phase C recompute + highway, in-place H.
//   Last layer: out[b][d] f32 at t=len-1 only; non-target spans early-exit.

typedef float f32x4 __attribute__((ext_vector_type(4)));
typedef int   i32x4 __attribute__((ext_vector_type(4)));
typedef char  c8x4  __attribute__((ext_vector_type(4)));
typedef _Float16 f16;

#define SRU_B 16
#define SRU_T 2048
#define SRU_D 1024
#define SRU_L 4
#define SRU_N 3072          // 3*D
#define SPAN 256            // scan span per wave (8 waves cover T=2048)

#define A_SCALE 4096.0f     // h quant scale (|h| < 8)
#define W_SCALE 2048.0f     // w quant scale
#define Z2_INV  1.1920928955078125e-7f  // 2^-23 = 1/(4096*2048)
#define H_INV   2.44140625e-4f          // 1/4096

__device__ __forceinline__ void q16split(float v, float scale, signed char& hi,
                                         signed char& lo) {
  int q = __float2int_rn(v * scale);
  q = min(max(q, -32512), 32512);
  int h = (q + 128) >> 8;            // remainder in [-128,127]
  hi = (signed char)h;
  lo = (signed char)(q - (h << 8));
}

__device__ __forceinline__ void mfma_i8(i32x4& c, i32x4 a, i32x4 b) {
  asm("v_mfma_i32_16x16x64_i8 %0, %1, %2, %0" : "+v"(c) : "v"(a), "v"(b));
}

#define GLDS(g, l) __builtin_amdgcn_global_load_lds(                      \
    (const __attribute__((address_space(1))) void*)(g),                   \
    (__attribute__((address_space(3))) void*)(l), 16, 0, 0)

// ---- W convert: [L][D][3D] f32 -> transposed [L][3D][D] single i8 ----
__global__ void convert_w_kernel(const float* __restrict__ W,
                                 signed char* __restrict__ Wt8) {
  __shared__ float tile[32][33];
  const int l = blockIdx.z;
  const int n0 = blockIdx.x * 32, k0 = blockIdx.y * 32;
  const int tx = threadIdx.x & 31, ty = threadIdx.x >> 5; // ty 0..7
  const float* Wl = W + (size_t)l * SRU_D * SRU_N;
#pragma unroll
  for (int i = 0; i < 32; i += 8)
    tile[ty + i][tx] = Wl[(size_t)(k0 + ty + i) * SRU_N + n0 + tx];
  __syncthreads();
  const size_t ob = (size_t)l * SRU_N * SRU_D;
#pragma unroll
  for (int i = 0; i < 32; i += 8) {
    float v = tile[tx][ty + i];
    size_t o = ob + (size_t)(n0 + ty + i) * SRU_D + k0 + tx;
    Wt8[o] = (signed char)__float2int_rn(v * W_SCALE);
  }
}

// ---- x convert: [B][T][D] f32 -> H [B][T][D] i8 hi/lo (skip t>=len) ----
__global__ void convert_x_kernel(const float* __restrict__ x,
                                 const int* __restrict__ lengths,
                                 signed char* __restrict__ Hh,
                                 signed char* __restrict__ Hl) {
  const size_t i = (size_t)blockIdx.x * 256 + threadIdx.x;   // f32x4 index
  const int b = (int)(i >> 19), t = (int)((i >> 8) & 2047);
  if (t >= lengths[b]) return;
  f32x4 v = ((const f32x4*)x)[i];
  c8x4 hi, lo;
#pragma unroll
  for (int j = 0; j < 4; ++j) {
    signed char h, l;
    q16split(v[j], A_SCALE, h, l);
    hi[j] = h;
    lo[j] = l;
  }
  ((c8x4*)Hh)[i] = hi;
  ((c8x4*)Hl)[i] = lo;
}

// ---- GEMM + gate epilogue (2-product: ah.w -> acc1, al.w -> acc2) ----
// 1D grid, XCD-aware: block id -> (b, tb, bn) with xcd = (b+tb)&7.
// Tile-skip beyond lengths[b]; last layer skips zr blocks except len-1 tile.
// A: 2 LDS buffers, counted vmcnt + raw barrier pair. B: registers from L2.
__global__ __launch_bounds__(256, 2) void gemm2_kernel(
    const signed char* __restrict__ Ah, const signed char* __restrict__ Al,
    const signed char* __restrict__ Bq,
    const int* __restrict__ lengths, const float* __restrict__ bias,
    f16* __restrict__ Ux, f16* __restrict__ Uf, f16* __restrict__ Ur,
    int last) {
  const int id = blockIdx.x;
  const int xcd = id & 7;
  const int r = id >> 3;            // 0..767
  const int bn = r % 24;
  const int q = r / 24;             // 0..31
  const int b = q >> 1;
  const int tb = ((xcd - b) & 7) | ((q & 1) << 3);
  const int lenb = lengths[b];
  if (tb * 128 >= lenb) return;                   // uniform early exit
  if (last && bn >= 16) {                         // zr region, last layer
    if (((lenb - 1) >> 7) != tb) return;
  }
  const int bm = (b << 4) | tb;

  __shared__ __align__(16) signed char lAh[16384], lAl[16384];  // 2 bufs each
  const int tid = threadIdx.x;
  const int lane = tid & 63, wid = tid >> 6;
  const int wm = (wid >> 1) * 64, wn = (wid & 1) * 64;
  const int fr = lane & 15;
  // swizzled 16B-chunk byte offset for A ds_read: (cb ^ ((row>>1)&3))*16
  const int fko = ((lane >> 4) * 16) ^ (((lane >> 1) & 3) * 16);

  i32x4 acc1[4][4] = {};   // sum ah*w
  i32x4 acc2[4][4] = {};   // sum al*w

  const int sr = tid >> 2;                              // staging row 0..63
  const int sc = (((tid & 3) ^ ((tid >> 3) & 3)) * 16); // pre-swizzled chunk
  const size_t abase = ((size_t)b * SRU_T + tb * 128) * SRU_D;
  const signed char* gAh = Ah + abase + (size_t)sr * 1024 + sc;
  const signed char* gAl = Al + abase + (size_t)sr * 1024 + sc;
  // B fragment base: row = bn*128 + wn + fr, 16B chunk = lane>>4 (no swizzle)
  const signed char* gBv = Bq + (size_t)(bn * 128 + wn + fr) * 1024 +
                           ((lane >> 4) << 4);

  // exactly 4 GLDS per thread per stage (vmcnt accounting relies on this)
  auto stage = [&](int step, int bs) {
    const int k0 = step * 64;
    const int o = bs * 8192 + wid * 1024;
    GLDS(gAh + k0, &lAh[o]); GLDS(gAh + 65536 + k0, &lAh[o + 4096]);
    GLDS(gAl + k0, &lAl[o]); GLDS(gAl + 65536 + k0, &lAl[o + 4096]);
  };

  i32x4 bv[4];
  auto loadB = [&](int step) {
    const int kk = step * 64;
#pragma unroll
    for (int ni = 0; ni < 4; ++ni)
      bv[ni] = *(const i32x4*)(gBv + (ni << 14) + kk);
  };

  // prologue order matters for vmcnt FIFO accounting: S0, B0, S1
  stage(0, 0);
  loadB(0);
  stage(1, 1);
  for (int step = 0; step < 16; ++step) {
    const int cb = (step & 1) * 8192;
    // retire S(step) [and B(step)]; S(step+1) (4 loads) stays in flight
    if (step < 15) asm volatile("s_waitcnt vmcnt(4)" ::: "memory");
    else           asm volatile("s_waitcnt vmcnt(0)" ::: "memory");
    asm volatile("s_barrier" ::: "memory");   // buf[step&1] visible to all
    i32x4 ah[4], al[4];
#pragma unroll
    for (int i = 0; i < 4; ++i) {
      const int ro = cb + (wm + i * 16 + fr) * 64 + fko;
      ah[i] = *(const i32x4*)&lAh[ro];
      al[i] = *(const i32x4*)&lAl[ro];
    }
#pragma unroll
    for (int ni = 0; ni < 4; ++ni) {
#pragma unroll
      for (int mi = 0; mi < 4; ++mi) {
        mfma_i8(acc1[mi][ni], ah[mi], bv[ni]);
        mfma_i8(acc2[mi][ni], al[mi], bv[ni]);
      }
    }
    // all waves done reading buf[step&1] before overwriting it with step+2
    asm volatile("s_barrier" ::: "memory");
    if (step + 1 < 16) loadB(step + 1);          // B first (FIFO order),
    if (step + 2 < 16) stage(step + 2, step & 1);// then next A stage
  }

  // epilogue: z = (256*acc1 + acc2) * 2^-23
  const int urow0 = bm * 128 + wm + (lane >> 4) * 4;
  const int gcol = bn * 128 + wn + fr;
  const int region = gcol >> 10;
  const int d0 = gcol & 1023;
  if (region == 0) {
#pragma unroll
    for (int mi = 0; mi < 4; ++mi)
#pragma unroll
      for (int ni = 0; ni < 4; ++ni)
#pragma unroll
        for (int r2 = 0; r2 < 4; ++r2) {
          float z = (256.f * (float)acc1[mi][ni][r2] +
                     (float)acc2[mi][ni][r2]) * Z2_INV;
          Ux[((size_t)(urow0 + mi * 16 + r2) << 10) + d0 + ni * 16] = (f16)z;
        }
  } else {
    const float* bp = bias + (region == 2 ? SRU_D : 0);
    float bvv[4];
#pragma unroll
    for (int ni = 0; ni < 4; ++ni) bvv[ni] = bp[d0 + ni * 16];
    f16* dst = (region == 1) ? Uf : Ur;
#pragma unroll
    for (int mi = 0; mi < 4; ++mi)
#pragma unroll
      for (int ni = 0; ni < 4; ++ni)
#pragma unroll
        for (int r2 = 0; r2 < 4; ++r2) {
          float z = (256.f * (float)acc1[mi][ni][r2] +
                     (float)acc2[mi][ni][r2]) * Z2_INV;
          float s = 1.f / (1.f + __expf(-(z + bvv[ni])));
          dst[((size_t)(urow0 + mi * 16 + r2) << 10) + d0 + ni * 16] = (f16)s;
        }
  }
}

// ---- fused scan: 8 waves x 256-t spans; A: (P,L); LDS combine; C: recompute
// + highway in-place on H. Last layer: out[b][d] f32 at t=len-1 only; spans
// not containing len-1 exit after their LDS contribution. ----
__global__ __launch_bounds__(512) void scan_kernel(
    const f16* __restrict__ Ux, const f16* __restrict__ Uf,
    const f16* __restrict__ Ur,
    const int* __restrict__ lengths,
    signed char* __restrict__ Hh, signed char* __restrict__ Hl,
    float* __restrict__ out, int last) {
  __shared__ float sP[8][64], sL[8][64];
  const int dblk = blockIdx.x, b = blockIdx.y;
  const int lane = threadIdx.x & 63, w = threadIdx.x >> 6;
  const int d = (dblk << 6) + lane;
  const int lenb = lengths[b];
  const int start = w * SPAN;
  const size_t rbase = (((size_t)b * SRU_T + start) << 10) + d;

  float P = 1.f, Lv = 0.f;
  if (start < lenb) {
    const int nbt = (min(SPAN, lenb - start) + 7) >> 3;   // batches of 8
    const f16* Xr = Ux + rbase;
    const f16* Fr = Uf + rbase;
    float xt_n[8], ff_n[8];
#pragma unroll
    for (int j = 0; j < 8; ++j) {
      xt_n[j] = (float)Xr[(size_t)j << 10];
      ff_n[j] = (float)Fr[(size_t)j << 10];
    }
    for (int bt = 0; bt < nbt; ++bt) {
      float xt[8], ff[8];
#pragma unroll
      for (int j = 0; j < 8; ++j) { xt[j] = xt_n[j]; ff[j] = ff_n[j]; }
      if (bt + 1 < nbt) {
        const size_t o2 = (size_t)((bt + 1) * 8) << 10;
#pragma unroll
        for (int j = 0; j < 8; ++j) {
          xt_n[j] = (float)Xr[o2 + ((size_t)j << 10)];
          ff_n[j] = (float)Fr[o2 + ((size_t)j << 10)];
        }
      }
#pragma unroll
      for (int j = 0; j < 8; ++j) {
        Lv = ff[j] * Lv + (1.f - ff[j]) * xt[j];
        P *= ff[j];
      }
    }
  }
  sP[w][lane] = P;
  sL[w][lane] = Lv;
  __syncthreads();                   // no barriers below this point
  if (start >= lenb) return;
  if (last && (lenb - 1 < start || lenb - 1 >= start + SPAN)) return;

  float c = 0.f;
#pragma unroll
  for (int j = 0; j < 8; ++j)
    if (j < w) c = sP[j][lane] * c + sL[j][lane];

  const int nbt = (min(SPAN, lenb - start) + 7) >> 3;
  const f16* Xr = Ux + rbase;
  const f16* Fr = Uf + rbase;
  const f16* Rr = Ur + rbase;
  signed char* ph = Hh + rbase;
  signed char* pl = Hl + rbase;

  float xt_n[8], ff_n[8], rr_n[8], hv_n[8];
#pragma unroll
  for (int j = 0; j < 8; ++j) {
    xt_n[j] = (float)Xr[(size_t)j << 10];
    ff_n[j] = (float)Fr[(size_t)j << 10];
    rr_n[j] = (float)Rr[(size_t)j << 10];
    hv_n[j] = (float)((int)ph[(size_t)j << 10] * 256 + (int)pl[(size_t)j << 10]) * H_INV;
  }
  for (int bt = 0; bt < nbt; ++bt) {
    float xt[8], ff[8], rr[8], hv[8];
#pragma unroll
    for (int j = 0; j < 8; ++j) {
      xt[j] = xt_n[j]; ff[j] = ff_n[j]; rr[j] = rr_n[j]; hv[j] = hv_n[j];
    }
    if (bt + 1 < nbt) {
      const size_t o2 = (size_t)((bt + 1) * 8) << 10;
#pragma unroll
      for (int j = 0; j < 8; ++j) {
        xt_n[j] = (float)Xr[o2 + ((size_t)j << 10)];
        ff_n[j] = (float)Fr[o2 + ((size_t)j << 10)];
        rr_n[j] = (float)Rr[o2 + ((size_t)j << 10)];
        hv_n[j] = (float)((int)ph[o2 + ((size_t)j << 10)] * 256 +
                          (int)pl[o2 + ((size_t)j << 10)]) * H_INV;
      }
    }
    signed char* wh = ph + ((size_t)(bt * 8) << 10);
    signed char* wl = pl + ((size_t)(bt * 8) << 10);
#pragma unroll
    for (int j = 0; j < 8; ++j) {
      c = ff[j] * c + (1.f - ff[j]) * xt[j];
      const int t = start + bt * 8 + j;
      if (last) {
        if (t == lenb - 1) {         // final output directly, f32
          float e = __expf(-2.f * fabsf(c));
          float th = copysignf((1.f - e) / (1.f + e), c);
          out[(b << 10) + d] = rr[j] * th + (1.f - rr[j]) * hv[j];
        }
      } else if (t < lenb) {
        float e = __expf(-2.f * fabsf(c));
        float th = copysignf((1.f - e) / (1.f + e), c);
        float o = rr[j] * th + (1.f - rr[j]) * hv[j];
        signed char oh, ol;
        q16split(o, A_SCALE, oh, ol);
        wh[(size_t)j << 10] = oh;
        wl[(size_t)j << 10] = ol;
      }
    }
  }
}

extern "C" void kernel_launch(void* const* d_in, const int* in_sizes, int n_in,
                              void* d_out, int out_size, void* d_ws, size_t ws_size,
                              hipStream_t stream) {
  const float* x = (const float*)d_in[0];
  const int* lengths = (const int*)d_in[1];
  const float* W = (const float*)d_in[2];
  const float* bias = (const float*)d_in[3];
  float* out = (float*)d_out;

  char* ws = (char*)d_ws;
  size_t off = 0;
  auto alloc = [&](size_t n) { void* p = ws + off; off += (n + 255) & ~(size_t)255; return p; };
  signed char* Hh  = (signed char*)alloc((size_t)SRU_T * SRU_B * SRU_D);     // 32MB
  signed char* Hl  = (signed char*)alloc((size_t)SRU_T * SRU_B * SRU_D);     // 32MB
  signed char* Wt8 = (signed char*)alloc((size_t)SRU_L * SRU_N * SRU_D);     // 12MB
  f16*   Ux   = (f16*)alloc((size_t)SRU_T * SRU_B * SRU_D * 2);              // 64MB
  f16*   Uf   = (f16*)alloc((size_t)SRU_T * SRU_B * SRU_D * 2);              // 64MB
  f16*   Ur   = (f16*)alloc((size_t)SRU_T * SRU_B * SRU_D * 2);              // 64MB

  hipLaunchKernelGGL(convert_w_kernel, dim3(SRU_N / 32, SRU_D / 32, SRU_L), dim3(256), 0, stream,
                     W, Wt8);
  hipLaunchKernelGGL(convert_x_kernel, dim3((SRU_B * SRU_T * SRU_D / 4) / 256), dim3(256), 0, stream,
                     x, lengths, Hh, Hl);

  for (int l = 0; l < SRU_L; ++l) {
    const signed char* Bq = Wt8 + (size_t)l * SRU_N * SRU_D;
    const float* bl_ = bias + (size_t)l * 2 * SRU_D;
    const int last = (l == SRU_L - 1) ? 1 : 0;
    hipLaunchKernelGGL(gemm2_kernel, dim3(24 * 256), dim3(256), 0, stream,
                       Hh, Hl, Bq, lengths, bl_, Ux, Uf, Ur, last);
    hipLaunchKernelGGL(scan_kernel, dim3(SRU_D / 64, SRU_B), dim3(512), 0, stream,
                       Ux, Uf, Ur, lengths, Hh, Hl, out, last);
  }
}

// Round 16
// 843.315 us; speedup vs baseline: 1.1606x; 1.1606x over previous
//
#include <hip/hip_runtime.h>

// SRU forward, MI355X. B=16, T=2048, D=1024, L=4.  [R14 config — validated]
// H stored as int16-split i8 pair (scale 4096). W single i8 (scale 2^11).
// GEMM: 2-product i8 MFMA (ah.w, al.w), exact int32 acc, 128x128 tile,
//   4 waves, BK=64, 2-buffer K-loop with COUNTED vmcnt(6) + raw s_barrier
//   pairs (no full vmcnt drain in-loop). __launch_bounds__(256,2).
//   LDS XOR-swizzle both-sides; fused epilogue (Ux raw f16, Uf/Ur sigmoid'd
//   f16); per-b length tile-skip; last layer computes zr only for len-1 tile.
//   XCD-aware 1D grid (xcd = (b+tb)&7).
// CLOSED levers (measured): (256,3) -> AccVGPR spills (R11); coarse 8-phase
//   -> -26% (R10); B-direct-from-global -> -39% (R15, L2 exposure).
// Scan: ONE kernel per layer: 8 waves x 256-t spans; phase A per-span (P,L),
//   LDS combine -> exact c_init, phase C recompute + highway, in-place H.
//   Last layer: out[b][d] f32 at t=len-1 only; non-target spans early-exit.

typedef float f32x4 __attribute__((ext_vector_type(4)));
typedef int   i32x4 __attribute__((ext_vector_type(4)));
typedef char  c8x4  __attribute__((ext_vector_type(4)));
typedef _Float16 f16;

#define SRU_B 16
#define SRU_T 2048
#define SRU_D 1024
#define SRU_L 4
#define SRU_N 3072          // 3*D
#define SPAN 256            // scan span per wave (8 waves cover T=2048)

#define A_SCALE 4096.0f     // h quant scale (|h| < 8)
#define W_SCALE 2048.0f     // w quant scale
#define Z2_INV  1.1920928955078125e-7f  // 2^-23 = 1/(4096*2048)
#define H_INV   2.44140625e-4f          // 1/4096

__device__ __forceinline__ void q16split(float v, float scale, signed char& hi,
                                         signed char& lo) {
  int q = __float2int_rn(v * scale);
  q = min(max(q, -32512), 32512);
  int h = (q + 128) >> 8;            // remainder in [-128,127]
  hi = (signed char)h;
  lo = (signed char)(q - (h << 8));
}

__device__ __forceinline__ void mfma_i8(i32x4& c, i32x4 a, i32x4 b) {
  asm("v_mfma_i32_16x16x64_i8 %0, %1, %2, %0" : "+v"(c) : "v"(a), "v"(b));
}

#define GLDS(g, l) __builtin_amdgcn_global_load_lds(                      \
    (const __attribute__((address_space(1))) void*)(g),                   \
    (__attribute__((address_space(3))) void*)(l), 16, 0, 0)

// ---- W convert: [L][D][3D] f32 -> transposed [L][3D][D] single i8 ----
__global__ void convert_w_kernel(const float* __restrict__ W,
                                 signed char* __restrict__ Wt8) {
  __shared__ float tile[32][33];
  const int l = blockIdx.z;
  const int n0 = blockIdx.x * 32, k0 = blockIdx.y * 32;
  const int tx = threadIdx.x & 31, ty = threadIdx.x >> 5; // ty 0..7
  const float* Wl = W + (size_t)l * SRU_D * SRU_N;
#pragma unroll
  for (int i = 0; i < 32; i += 8)
    tile[ty + i][tx] = Wl[(size_t)(k0 + ty + i) * SRU_N + n0 + tx];
  __syncthreads();
  const size_t ob = (size_t)l * SRU_N * SRU_D;
#pragma unroll
  for (int i = 0; i < 32; i += 8) {
    float v = tile[tx][ty + i];
    size_t o = ob + (size_t)(n0 + ty + i) * SRU_D + k0 + tx;
    Wt8[o] = (signed char)__float2int_rn(v * W_SCALE);
  }
}

// ---- x convert: [B][T][D] f32 -> H [B][T][D] i8 hi/lo (skip t>=len) ----
__global__ void convert_x_kernel(const float* __restrict__ x,
                                 const int* __restrict__ lengths,
                                 signed char* __restrict__ Hh,
                                 signed char* __restrict__ Hl) {
  const size_t i = (size_t)blockIdx.x * 256 + threadIdx.x;   // f32x4 index
  const int b = (int)(i >> 19), t = (int)((i >> 8) & 2047);
  if (t >= lengths[b]) return;
  f32x4 v = ((const f32x4*)x)[i];
  c8x4 hi, lo;
#pragma unroll
  for (int j = 0; j < 4; ++j) {
    signed char h, l;
    q16split(v[j], A_SCALE, h, l);
    hi[j] = h;
    lo[j] = l;
  }
  ((c8x4*)Hh)[i] = hi;
  ((c8x4*)Hl)[i] = lo;
}

// ---- GEMM + gate epilogue (2-product: ah.w -> acc1, al.w -> acc2) ----
// 1D grid, XCD-aware: block id -> (b, tb, bn) with xcd = (b+tb)&7.
// Tile-skip beyond lengths[b]; last layer skips zr blocks except len-1 tile.
// K-loop: counted vmcnt(6) + raw barrier pair per step, 2 LDS buffers.
__global__ __launch_bounds__(256, 2) void gemm2_kernel(
    const signed char* __restrict__ Ah, const signed char* __restrict__ Al,
    const signed char* __restrict__ Bq,
    const int* __restrict__ lengths, const float* __restrict__ bias,
    f16* __restrict__ Ux, f16* __restrict__ Uf, f16* __restrict__ Ur,
    int last) {
  const int id = blockIdx.x;
  const int xcd = id & 7;
  const int r = id >> 3;            // 0..767
  const int bn = r % 24;
  const int q = r / 24;             // 0..31
  const int b = q >> 1;
  const int tb = ((xcd - b) & 7) | ((q & 1) << 3);
  const int lenb = lengths[b];
  if (tb * 128 >= lenb) return;                   // uniform early exit
  if (last && bn >= 16) {                         // zr region, last layer
    if (((lenb - 1) >> 7) != tb) return;
  }
  const int bm = (b << 4) | tb;

  __shared__ __align__(16) signed char lAh[16384], lAl[16384], lB[16384];
  const int tid = threadIdx.x;
  const int lane = tid & 63, wid = tid >> 6;
  const int wm = (wid >> 1) * 64, wn = (wid & 1) * 64;
  const int fr = lane & 15;
  // swizzled 16B-chunk byte offset for ds_read: (cb ^ ((row>>1)&3))*16
  const int fko = ((lane >> 4) * 16) ^ (((lane >> 1) & 3) * 16);

  i32x4 acc1[4][4] = {};   // sum ah*w
  i32x4 acc2[4][4] = {};   // sum al*w

  const int sr = tid >> 2;                              // staging row 0..63
  const int sc = (((tid & 3) ^ ((tid >> 3) & 3)) * 16); // pre-swizzled chunk
  const size_t abase = ((size_t)b * SRU_T + tb * 128) * SRU_D;
  const signed char* gAh = Ah + abase + (size_t)sr * 1024 + sc;
  const signed char* gAl = Al + abase + (size_t)sr * 1024 + sc;
  const signed char* gB  = Bq + (size_t)(bn * 128 + sr) * 1024 + sc;

  // exactly 6 GLDS per thread per stage (vmcnt accounting relies on this)
  auto stage = [&](int step, int bs) {
    const int k0 = step * 64;
    const int o = bs * 8192 + wid * 1024;
    GLDS(gAh + k0, &lAh[o]); GLDS(gAh + 65536 + k0, &lAh[o + 4096]);
    GLDS(gAl + k0, &lAl[o]); GLDS(gAl + 65536 + k0, &lAl[o + 4096]);
    GLDS(gB  + k0, &lB[o]);  GLDS(gB  + 65536 + k0, &lB[o + 4096]);
  };

  stage(0, 0);
  stage(1, 1);
  for (int step = 0; step < 16; ++step) {
    const int cb = (step & 1) * 8192;
    // wait only for stage(step)'s 6 loads; stage(step+1)'s 6 stay in flight
    if (step < 15) asm volatile("s_waitcnt vmcnt(6)" ::: "memory");
    else           asm volatile("s_waitcnt vmcnt(0)" ::: "memory");
    asm volatile("s_barrier" ::: "memory");   // buf[step&1] visible to all
    i32x4 ah[4], al[4];
#pragma unroll
    for (int i = 0; i < 4; ++i) {
      const int ro = cb + (wm + i * 16 + fr) * 64 + fko;
      ah[i] = *(const i32x4*)&lAh[ro];
      al[i] = *(const i32x4*)&lAl[ro];
    }
#pragma unroll
    for (int ni = 0; ni < 4; ++ni) {
      const int ro = cb + (wn + ni * 16 + fr) * 64 + fko;
      i32x4 bv = *(const i32x4*)&lB[ro];
#pragma unroll
      for (int mi = 0; mi < 4; ++mi) {
        mfma_i8(acc1[mi][ni], ah[mi], bv);
        mfma_i8(acc2[mi][ni], al[mi], bv);
      }
    }
    // all waves done reading buf[step&1] before overwriting it with step+2
    asm volatile("s_barrier" ::: "memory");
    if (step + 2 < 16) stage(step + 2, step & 1);
  }

  // epilogue: z = (256*acc1 + acc2) * 2^-23
  const int urow0 = bm * 128 + wm + (lane >> 4) * 4;
  const int gcol = bn * 128 + wn + fr;
  const int region = gcol >> 10;
  const int d0 = gcol & 1023;
  if (region == 0) {
#pragma unroll
    for (int mi = 0; mi < 4; ++mi)
#pragma unroll
      for (int ni = 0; ni < 4; ++ni)
#pragma unroll
        for (int r2 = 0; r2 < 4; ++r2) {
          float z = (256.f * (float)acc1[mi][ni][r2] +
                     (float)acc2[mi][ni][r2]) * Z2_INV;
          Ux[((size_t)(urow0 + mi * 16 + r2) << 10) + d0 + ni * 16] = (f16)z;
        }
  } else {
    const float* bp = bias + (region == 2 ? SRU_D : 0);
    float bv[4];
#pragma unroll
    for (int ni = 0; ni < 4; ++ni) bv[ni] = bp[d0 + ni * 16];
    f16* dst = (region == 1) ? Uf : Ur;
#pragma unroll
    for (int mi = 0; mi < 4; ++mi)
#pragma unroll
      for (int ni = 0; ni < 4; ++ni)
#pragma unroll
        for (int r2 = 0; r2 < 4; ++r2) {
          float z = (256.f * (float)acc1[mi][ni][r2] +
                     (float)acc2[mi][ni][r2]) * Z2_INV;
          float s = 1.f / (1.f + __expf(-(z + bv[ni])));
          dst[((size_t)(urow0 + mi * 16 + r2) << 10) + d0 + ni * 16] = (f16)s;
        }
  }
}

// ---- fused scan: 8 waves x 256-t spans; A: (P,L); LDS combine; C: recompute
// + highway in-place on H. Last layer: out[b][d] f32 at t=len-1 only; spans
// not containing len-1 exit after their LDS contribution. ----
__global__ __launch_bounds__(512) void scan_kernel(
    const f16* __restrict__ Ux, const f16* __restrict__ Uf,
    const f16* __restrict__ Ur,
    const int* __restrict__ lengths,
    signed char* __restrict__ Hh, signed char* __restrict__ Hl,
    float* __restrict__ out, int last) {
  __shared__ float sP[8][64], sL[8][64];
  const int dblk = blockIdx.x, b = blockIdx.y;
  const int lane = threadIdx.x & 63, w = threadIdx.x >> 6;
  const int d = (dblk << 6) + lane;
  const int lenb = lengths[b];
  const int start = w * SPAN;
  const size_t rbase = (((size_t)b * SRU_T + start) << 10) + d;

  float P = 1.f, Lv = 0.f;
  if (start < lenb) {
    const int nbt = (min(SPAN, lenb - start) + 7) >> 3;   // batches of 8
    const f16* Xr = Ux + rbase;
    const f16* Fr = Uf + rbase;
    float xt_n[8], ff_n[8];
#pragma unroll
    for (int j = 0; j < 8; ++j) {
      xt_n[j] = (float)Xr[(size_t)j << 10];
      ff_n[j] = (float)Fr[(size_t)j << 10];
    }
    for (int bt = 0; bt < nbt; ++bt) {
      float xt[8], ff[8];
#pragma unroll
      for (int j = 0; j < 8; ++j) { xt[j] = xt_n[j]; ff[j] = ff_n[j]; }
      if (bt + 1 < nbt) {
        const size_t o2 = (size_t)((bt + 1) * 8) << 10;
#pragma unroll
        for (int j = 0; j < 8; ++j) {
          xt_n[j] = (float)Xr[o2 + ((size_t)j << 10)];
          ff_n[j] = (float)Fr[o2 + ((size_t)j << 10)];
        }
      }
#pragma unroll
      for (int j = 0; j < 8; ++j) {
        Lv = ff[j] * Lv + (1.f - ff[j]) * xt[j];
        P *= ff[j];
      }
    }
  }
  sP[w][lane] = P;
  sL[w][lane] = Lv;
  __syncthreads();                   // no barriers below this point
  if (start >= lenb) return;
  if (last && (lenb - 1 < start || lenb - 1 >= start + SPAN)) return;

  float c = 0.f;
#pragma unroll
  for (int j = 0; j < 8; ++j)
    if (j < w) c = sP[j][lane] * c + sL[j][lane];

  const int nbt = (min(SPAN, lenb - start) + 7) >> 3;
  const f16* Xr = Ux + rbase;
  const f16* Fr = Uf + rbase;
  const f16* Rr = Ur + rbase;
  signed char* ph = Hh + rbase;
  signed char* pl = Hl + rbase;

  float xt_n[8], ff_n[8], rr_n[8], hv_n[8];
#pragma unroll
  for (int j = 0; j < 8; ++j) {
    xt_n[j] = (float)Xr[(size_t)j << 10];
    ff_n[j] = (float)Fr[(size_t)j << 10];
    rr_n[j] = (float)Rr[(size_t)j << 10];
    hv_n[j] = (float)((int)ph[(size_t)j << 10] * 256 + (int)pl[(size_t)j << 10]) * H_INV;
  }
  for (int bt = 0; bt < nbt; ++bt) {
    float xt[8], ff[8], rr[8], hv[8];
#pragma unroll
    for (int j = 0; j < 8; ++j) {
      xt[j] = xt_n[j]; ff[j] = ff_n[j]; rr[j] = rr_n[j]; hv[j] = hv_n[j];
    }
    if (bt + 1 < nbt) {
      const size_t o2 = (size_t)((bt + 1) * 8) << 10;
#pragma unroll
      for (int j = 0; j < 8; ++j) {
        xt_n[j] = (float)Xr[o2 + ((size_t)j << 10)];
        ff_n[j] = (float)Fr[o2 + ((size_t)j << 10)];
        rr_n[j] = (float)Rr[o2 + ((size_t)j << 10)];
        hv_n[j] = (float)((int)ph[o2 + ((size_t)j << 10)] * 256 +
                          (int)pl[o2 + ((size_t)j << 10)]) * H_INV;
      }
    }
    signed char* wh = ph + ((size_t)(bt * 8) << 10);
    signed char* wl = pl + ((size_t)(bt * 8) << 10);
#pragma unroll
    for (int j = 0; j < 8; ++j) {
      c = ff[j] * c + (1.f - ff[j]) * xt[j];
      const int t = start + bt * 8 + j;
      if (last) {
        if (t == lenb - 1) {         // final output directly, f32
          float e = __expf(-2.f * fabsf(c));
          float th = copysignf((1.f - e) / (1.f + e), c);
          out[(b << 10) + d] = rr[j] * th + (1.f - rr[j]) * hv[j];
        }
      } else if (t < lenb) {
        float e = __expf(-2.f * fabsf(c));
        float th = copysignf((1.f - e) / (1.f + e), c);
        float o = rr[j] * th + (1.f - rr[j]) * hv[j];
        signed char oh, ol;
        q16split(o, A_SCALE, oh, ol);
        wh[(size_t)j << 10] = oh;
        wl[(size_t)j << 10] = ol;
      }
    }
  }
}

extern "C" void kernel_launch(void* const* d_in, const int* in_sizes, int n_in,
                              void* d_out, int out_size, void* d_ws, size_t ws_size,
                              hipStream_t stream) {
  const float* x = (const float*)d_in[0];
  const int* lengths = (const int*)d_in[1];
  const float* W = (const float*)d_in[2];
  const float* bias = (const float*)d_in[3];
  float* out = (float*)d_out;

  char* ws = (char*)d_ws;
  size_t off = 0;
  auto alloc = [&](size_t n) { void* p = ws + off; off += (n + 255) & ~(size_t)255; return p; };
  signed char* Hh  = (signed char*)alloc((size_t)SRU_T * SRU_B * SRU_D);     // 32MB
  signed char* Hl  = (signed char*)alloc((size_t)SRU_T * SRU_B * SRU_D);     // 32MB
  signed char* Wt8 = (signed char*)alloc((size_t)SRU_L * SRU_N * SRU_D);     // 12MB
  f16*   Ux   = (f16*)alloc((size_t)SRU_T * SRU_B * SRU_D * 2);              // 64MB
  f16*   Uf   = (f16*)alloc((size_t)SRU_T * SRU_B * SRU_D * 2);              // 64MB
  f16*   Ur   = (f16*)alloc((size_t)SRU_T * SRU_B * SRU_D * 2);              // 64MB

  hipLaunchKernelGGL(convert_w_kernel, dim3(SRU_N / 32, SRU_D / 32, SRU_L), dim3(256), 0, stream,
                     W, Wt8);
  hipLaunchKernelGGL(convert_x_kernel, dim3((SRU_B * SRU_T * SRU_D / 4) / 256), dim3(256), 0, stream,
                     x, lengths, Hh, Hl);

  for (int l = 0; l < SRU_L; ++l) {
    const signed char* Bq = Wt8 + (size_t)l * SRU_N * SRU_D;
    const float* bl_ = bias + (size_t)l * 2 * SRU_D;
    const int last = (l == SRU_L - 1) ? 1 : 0;
    hipLaunchKernelGGL(gemm2_kernel, dim3(24 * 256), dim3(256), 0, stream,
                       Hh, Hl, Bq, lengths, bl_, Ux, Uf, Ur, last);
    hipLaunchKernelGGL(scan_kernel, dim3(SRU_D / 64, SRU_B), dim3(512), 0, stream,
                       Ux, Uf, Ur, lengths, Hh, Hl, out, last);
  }
}

// Round 17
// 725.062 us; speedup vs baseline: 1.3499x; 1.1631x over previous
//
#include <hip/hip_runtime.h>

// SRU forward, MI355X. B=16, T=2048, D=1024, L=4.
// H stored as int16-split i8 pair (scale 4096). W single i8 (scale 2^11).
// GEMM [R14 config, validated]: 2-product i8 MFMA (ah.w, al.w), exact int32
//   acc, 128x128 tile, 4 waves, BK=64, 2-buffer K-loop with COUNTED vmcnt(6)
//   + raw s_barrier pairs. __launch_bounds__(256,2). LDS XOR-swizzle
//   both-sides; fused epilogue (Ux raw f16, Uf/Ur sigmoid'd f16); per-b
//   length tile-skip; last layer computes zr only for len-1 tile.
//   XCD-aware 1D grid (xcd = (b+tb)&7).
// CLOSED levers (measured): (256,3) -> AccVGPR spills (R11); coarse 8-phase
//   -> -26% (R10); B-direct-from-global -> -39% (R15, L2 exposure).
// Scan: SPAN=128, 16 waves/block (1024 thr) -> 50% occupancy (was 25%);
//   phase A per-span (P,L), LDS combine over 16 summaries -> exact c_init,
//   phase C recompute + highway in-place. Last layer: out[b][d] f32 at
//   t=len-1 only; non-target spans early-exit after LDS contribution.

typedef float f32x4 __attribute__((ext_vector_type(4)));
typedef int   i32x4 __attribute__((ext_vector_type(4)));
typedef char  c8x4  __attribute__((ext_vector_type(4)));
typedef _Float16 f16;

#define SRU_B 16
#define SRU_T 2048
#define SRU_D 1024
#define SRU_L 4
#define SRU_N 3072          // 3*D
#define SPAN 128            // scan span per wave (16 waves cover T=2048)
#define NW   16             // waves per scan block

#define A_SCALE 4096.0f     // h quant scale (|h| < 8)
#define W_SCALE 2048.0f     // w quant scale
#define Z2_INV  1.1920928955078125e-7f  // 2^-23 = 1/(4096*2048)
#define H_INV   2.44140625e-4f          // 1/4096

__device__ __forceinline__ void q16split(float v, float scale, signed char& hi,
                                         signed char& lo) {
  int q = __float2int_rn(v * scale);
  q = min(max(q, -32512), 32512);
  int h = (q + 128) >> 8;            // remainder in [-128,127]
  hi = (signed char)h;
  lo = (signed char)(q - (h << 8));
}

__device__ __forceinline__ void mfma_i8(i32x4& c, i32x4 a, i32x4 b) {
  asm("v_mfma_i32_16x16x64_i8 %0, %1, %2, %0" : "+v"(c) : "v"(a), "v"(b));
}

#define GLDS(g, l) __builtin_amdgcn_global_load_lds(                      \
    (const __attribute__((address_space(1))) void*)(g),                   \
    (__attribute__((address_space(3))) void*)(l), 16, 0, 0)

// ---- W convert: [L][D][3D] f32 -> transposed [L][3D][D] single i8 ----
__global__ void convert_w_kernel(const float* __restrict__ W,
                                 signed char* __restrict__ Wt8) {
  __shared__ float tile[32][33];
  const int l = blockIdx.z;
  const int n0 = blockIdx.x * 32, k0 = blockIdx.y * 32;
  const int tx = threadIdx.x & 31, ty = threadIdx.x >> 5; // ty 0..7
  const float* Wl = W + (size_t)l * SRU_D * SRU_N;
#pragma unroll
  for (int i = 0; i < 32; i += 8)
    tile[ty + i][tx] = Wl[(size_t)(k0 + ty + i) * SRU_N + n0 + tx];
  __syncthreads();
  const size_t ob = (size_t)l * SRU_N * SRU_D;
#pragma unroll
  for (int i = 0; i < 32; i += 8) {
    float v = tile[tx][ty + i];
    size_t o = ob + (size_t)(n0 + ty + i) * SRU_D + k0 + tx;
    Wt8[o] = (signed char)__float2int_rn(v * W_SCALE);
  }
}

// ---- x convert: [B][T][D] f32 -> H [B][T][D] i8 hi/lo (skip t>=len) ----
__global__ void convert_x_kernel(const float* __restrict__ x,
                                 const int* __restrict__ lengths,
                                 signed char* __restrict__ Hh,
                                 signed char* __restrict__ Hl) {
  const size_t i = (size_t)blockIdx.x * 256 + threadIdx.x;   // f32x4 index
  const int b = (int)(i >> 19), t = (int)((i >> 8) & 2047);
  if (t >= lengths[b]) return;
  f32x4 v = ((const f32x4*)x)[i];
  c8x4 hi, lo;
#pragma unroll
  for (int j = 0; j < 4; ++j) {
    signed char h, l;
    q16split(v[j], A_SCALE, h, l);
    hi[j] = h;
    lo[j] = l;
  }
  ((c8x4*)Hh)[i] = hi;
  ((c8x4*)Hl)[i] = lo;
}

// ---- GEMM + gate epilogue (2-product: ah.w -> acc1, al.w -> acc2) ----
// 1D grid, XCD-aware: block id -> (b, tb, bn) with xcd = (b+tb)&7.
// Tile-skip beyond lengths[b]; last layer skips zr blocks except len-1 tile.
// K-loop: counted vmcnt(6) + raw barrier pair per step, 2 LDS buffers.
__global__ __launch_bounds__(256, 2) void gemm2_kernel(
    const signed char* __restrict__ Ah, const signed char* __restrict__ Al,
    const signed char* __restrict__ Bq,
    const int* __restrict__ lengths, const float* __restrict__ bias,
    f16* __restrict__ Ux, f16* __restrict__ Uf, f16* __restrict__ Ur,
    int last) {
  const int id = blockIdx.x;
  const int xcd = id & 7;
  const int r = id >> 3;            // 0..767
  const int bn = r % 24;
  const int q = r / 24;             // 0..31
  const int b = q >> 1;
  const int tb = ((xcd - b) & 7) | ((q & 1) << 3);
  const int lenb = lengths[b];
  if (tb * 128 >= lenb) return;                   // uniform early exit
  if (last && bn >= 16) {                         // zr region, last layer
    if (((lenb - 1) >> 7) != tb) return;
  }
  const int bm = (b << 4) | tb;

  __shared__ __align__(16) signed char lAh[16384], lAl[16384], lB[16384];
  const int tid = threadIdx.x;
  const int lane = tid & 63, wid = tid >> 6;
  const int wm = (wid >> 1) * 64, wn = (wid & 1) * 64;
  const int fr = lane & 15;
  // swizzled 16B-chunk byte offset for ds_read: (cb ^ ((row>>1)&3))*16
  const int fko = ((lane >> 4) * 16) ^ (((lane >> 1) & 3) * 16);

  i32x4 acc1[4][4] = {};   // sum ah*w
  i32x4 acc2[4][4] = {};   // sum al*w

  const int sr = tid >> 2;                              // staging row 0..63
  const int sc = (((tid & 3) ^ ((tid >> 3) & 3)) * 16); // pre-swizzled chunk
  const size_t abase = ((size_t)b * SRU_T + tb * 128) * SRU_D;
  const signed char* gAh = Ah + abase + (size_t)sr * 1024 + sc;
  const signed char* gAl = Al + abase + (size_t)sr * 1024 + sc;
  const signed char* gB  = Bq + (size_t)(bn * 128 + sr) * 1024 + sc;

  // exactly 6 GLDS per thread per stage (vmcnt accounting relies on this)
  auto stage = [&](int step, int bs) {
    const int k0 = step * 64;
    const int o = bs * 8192 + wid * 1024;
    GLDS(gAh + k0, &lAh[o]); GLDS(gAh + 65536 + k0, &lAh[o + 4096]);
    GLDS(gAl + k0, &lAl[o]); GLDS(gAl + 65536 + k0, &lAl[o + 4096]);
    GLDS(gB  + k0, &lB[o]);  GLDS(gB  + 65536 + k0, &lB[o + 4096]);
  };

  stage(0, 0);
  stage(1, 1);
  for (int step = 0; step < 16; ++step) {
    const int cb = (step & 1) * 8192;
    // wait only for stage(step)'s 6 loads; stage(step+1)'s 6 stay in flight
    if (step < 15) asm volatile("s_waitcnt vmcnt(6)" ::: "memory");
    else           asm volatile("s_waitcnt vmcnt(0)" ::: "memory");
    asm volatile("s_barrier" ::: "memory");   // buf[step&1] visible to all
    i32x4 ah[4], al[4];
#pragma unroll
    for (int i = 0; i < 4; ++i) {
      const int ro = cb + (wm + i * 16 + fr) * 64 + fko;
      ah[i] = *(const i32x4*)&lAh[ro];
      al[i] = *(const i32x4*)&lAl[ro];
    }
#pragma unroll
    for (int ni = 0; ni < 4; ++ni) {
      const int ro = cb + (wn + ni * 16 + fr) * 64 + fko;
      i32x4 bv = *(const i32x4*)&lB[ro];
#pragma unroll
      for (int mi = 0; mi < 4; ++mi) {
        mfma_i8(acc1[mi][ni], ah[mi], bv);
        mfma_i8(acc2[mi][ni], al[mi], bv);
      }
    }
    // all waves done reading buf[step&1] before overwriting it with step+2
    asm volatile("s_barrier" ::: "memory");
    if (step + 2 < 16) stage(step + 2, step & 1);
  }

  // epilogue: z = (256*acc1 + acc2) * 2^-23
  const int urow0 = bm * 128 + wm + (lane >> 4) * 4;
  const int gcol = bn * 128 + wn + fr;
  const int region = gcol >> 10;
  const int d0 = gcol & 1023;
  if (region == 0) {
#pragma unroll
    for (int mi = 0; mi < 4; ++mi)
#pragma unroll
      for (int ni = 0; ni < 4; ++ni)
#pragma unroll
        for (int r2 = 0; r2 < 4; ++r2) {
          float z = (256.f * (float)acc1[mi][ni][r2] +
                     (float)acc2[mi][ni][r2]) * Z2_INV;
          Ux[((size_t)(urow0 + mi * 16 + r2) << 10) + d0 + ni * 16] = (f16)z;
        }
  } else {
    const float* bp = bias + (region == 2 ? SRU_D : 0);
    float bv[4];
#pragma unroll
    for (int ni = 0; ni < 4; ++ni) bv[ni] = bp[d0 + ni * 16];
    f16* dst = (region == 1) ? Uf : Ur;
#pragma unroll
    for (int mi = 0; mi < 4; ++mi)
#pragma unroll
      for (int ni = 0; ni < 4; ++ni)
#pragma unroll
        for (int r2 = 0; r2 < 4; ++r2) {
          float z = (256.f * (float)acc1[mi][ni][r2] +
                     (float)acc2[mi][ni][r2]) * Z2_INV;
          float s = 1.f / (1.f + __expf(-(z + bv[ni])));
          dst[((size_t)(urow0 + mi * 16 + r2) << 10) + d0 + ni * 16] = (f16)s;
        }
  }
}

// ---- fused scan: 16 waves x 128-t spans; A: (P,L); LDS combine; C:
// recompute + highway in-place on H. Last layer: out[b][d] f32 at t=len-1
// only; spans not containing len-1 exit after their LDS contribution. ----
__global__ __launch_bounds__(1024) void scan_kernel(
    const f16* __restrict__ Ux, const f16* __restrict__ Uf,
    const f16* __restrict__ Ur,
    const int* __restrict__ lengths,
    signed char* __restrict__ Hh, signed char* __restrict__ Hl,
    float* __restrict__ out, int last) {
  __shared__ float sP[NW][64], sL[NW][64];
  const int dblk = blockIdx.x, b = blockIdx.y;
  const int lane = threadIdx.x & 63, w = threadIdx.x >> 6;
  const int d = (dblk << 6) + lane;
  const int lenb = lengths[b];
  const int start = w * SPAN;
  const size_t rbase = (((size_t)b * SRU_T + start) << 10) + d;

  float P = 1.f, Lv = 0.f;
  if (start < lenb) {
    const int nbt = (min(SPAN, lenb - start) + 7) >> 3;   // batches of 8
    const f16* Xr = Ux + rbase;
    const f16* Fr = Uf + rbase;
    float xt_n[8], ff_n[8];
#pragma unroll
    for (int j = 0; j < 8; ++j) {
      xt_n[j] = (float)Xr[(size_t)j << 10];
      ff_n[j] = (float)Fr[(size_t)j << 10];
    }
    for (int bt = 0; bt < nbt; ++bt) {
      float xt[8], ff[8];
#pragma unroll
      for (int j = 0; j < 8; ++j) { xt[j] = xt_n[j]; ff[j] = ff_n[j]; }
      if (bt + 1 < nbt) {
        const size_t o2 = (size_t)((bt + 1) * 8) << 10;
#pragma unroll
        for (int j = 0; j < 8; ++j) {
          xt_n[j] = (float)Xr[o2 + ((size_t)j << 10)];
          ff_n[j] = (float)Fr[o2 + ((size_t)j << 10)];
        }
      }
#pragma unroll
      for (int j = 0; j < 8; ++j) {
        Lv = ff[j] * Lv + (1.f - ff[j]) * xt[j];
        P *= ff[j];
      }
    }
  }
  sP[w][lane] = P;
  sL[w][lane] = Lv;
  __syncthreads();                   // no barriers below this point
  if (start >= lenb) return;
  if (last && (lenb - 1 < start || lenb - 1 >= start + SPAN)) return;

  float c = 0.f;
#pragma unroll
  for (int j = 0; j < NW; ++j)
    if (j < w) c = sP[j][lane] * c + sL[j][lane];

  const int nbt = (min(SPAN, lenb - start) + 7) >> 3;
  const f16* Xr = Ux + rbase;
  const f16* Fr = Uf + rbase;
  const f16* Rr = Ur + rbase;
  signed char* ph = Hh + rbase;
  signed char* pl = Hl + rbase;

  float xt_n[8], ff_n[8], rr_n[8], hv_n[8];
#pragma unroll
  for (int j = 0; j < 8; ++j) {
    xt_n[j] = (float)Xr[(size_t)j << 10];
    ff_n[j] = (float)Fr[(size_t)j << 10];
    rr_n[j] = (float)Rr[(size_t)j << 10];
    hv_n[j] = (float)((int)ph[(size_t)j << 10] * 256 + (int)pl[(size_t)j << 10]) * H_INV;
  }
  for (int bt = 0; bt < nbt; ++bt) {
    float xt[8], ff[8], rr[8], hv[8];
#pragma unroll
    for (int j = 0; j < 8; ++j) {
      xt[j] = xt_n[j]; ff[j] = ff_n[j]; rr[j] = rr_n[j]; hv[j] = hv_n[j];
    }
    if (bt + 1 < nbt) {
      const size_t o2 = (size_t)((bt + 1) * 8) << 10;
#pragma unroll
      for (int j = 0; j < 8; ++j) {
        xt_n[j] = (float)Xr[o2 + ((size_t)j << 10)];
        ff_n[j] = (float)Fr[o2 + ((size_t)j << 10)];
        rr_n[j] = (float)Rr[o2 + ((size_t)j << 10)];
        hv_n[j] = (float)((int)ph[o2 + ((size_t)j << 10)] * 256 +
                          (int)pl[o2 + ((size_t)j << 10)]) * H_INV;
      }
    }
    signed char* wh = ph + ((size_t)(bt * 8) << 10);
    signed char* wl = pl + ((size_t)(bt * 8) << 10);
#pragma unroll
    for (int j = 0; j < 8; ++j) {
      c = ff[j] * c + (1.f - ff[j]) * xt[j];
      const int t = start + bt * 8 + j;
      if (last) {
        if (t == lenb - 1) {         // final output directly, f32
          float e = __expf(-2.f * fabsf(c));
          float th = copysignf((1.f - e) / (1.f + e), c);
          out[(b << 10) + d] = rr[j] * th + (1.f - rr[j]) * hv[j];
        }
      } else if (t < lenb) {
        float e = __expf(-2.f * fabsf(c));
        float th = copysignf((1.f - e) / (1.f + e), c);
        float o = rr[j] * th + (1.f - rr[j]) * hv[j];
        signed char oh, ol;
        q16split(o, A_SCALE, oh, ol);
        wh[(size_t)j << 10] = oh;
        wl[(size_t)j << 10] = ol;
      }
    }
  }
}

extern "C" void kernel_launch(void* const* d_in, const int* in_sizes, int n_in,
                              void* d_out, int out_size, void* d_ws, size_t ws_size,
                              hipStream_t stream) {
  const float* x = (const float*)d_in[0];
  const int* lengths = (const int*)d_in[1];
  const float* W = (const float*)d_in[2];
  const float* bias = (const float*)d_in[3];
  float* out = (float*)d_out;

  char* ws = (char*)d_ws;
  size_t off = 0;
  auto alloc = [&](size_t n) { void* p = ws + off; off += (n + 255) & ~(size_t)255; return p; };
  signed char* Hh  = (signed char*)alloc((size_t)SRU_T * SRU_B * SRU_D);     // 32MB
  signed char* Hl  = (signed char*)alloc((size_t)SRU_T * SRU_B * SRU_D);     // 32MB
  signed char* Wt8 = (signed char*)alloc((size_t)SRU_L * SRU_N * SRU_D);     // 12MB
  f16*   Ux   = (f16*)alloc((size_t)SRU_T * SRU_B * SRU_D * 2);              // 64MB
  f16*   Uf   = (f16*)alloc((size_t)SRU_T * SRU_B * SRU_D * 2);              // 64MB
  f16*   Ur   = (f16*)alloc((size_t)SRU_T * SRU_B * SRU_D * 2);              // 64MB

  hipLaunchKernelGGL(convert_w_kernel, dim3(SRU_N / 32, SRU_D / 32, SRU_L), dim3(256), 0, stream,
                     W, Wt8);
  hipLaunchKernelGGL(convert_x_kernel, dim3((SRU_B * SRU_T * SRU_D / 4) / 256), dim3(256), 0, stream,
                     x, lengths, Hh, Hl);

  for (int l = 0; l < SRU_L; ++l) {
    const signed char* Bq = Wt8 + (size_t)l * SRU_N * SRU_D;
    const float* bl_ = bias + (size_t)l * 2 * SRU_D;
    const int last = (l == SRU_L - 1) ? 1 : 0;
    hipLaunchKernelGGL(gemm2_kernel, dim3(24 * 256), dim3(256), 0, stream,
                       Hh, Hl, Bq, lengths, bl_, Ux, Uf, Ur, last);
    hipLaunchKernelGGL(scan_kernel, dim3(SRU_D / 64, SRU_B), dim3(1024), 0, stream,
                       Ux, Uf, Ur, lengths, Hh, Hl, out, last);
  }
}